// Round 3
// baseline (452.234 us; speedup 1.0000x reference)
//
#include <hip/hip_runtime.h>
#include <stdint.h>

#define MASK_ID 103
#define CLS 30522
#define SEQ_L 128
#define NROWS 2048
#define BL 8192   // B*L

// ws layout: [0, NROWS) int rowcol; then 4 words accum: {swl, sw, sul, ticket}

// ---------------------------------------------------------------------------
// Kernel 1: row-major nonzero(masked == MASK_ID) -> packed (b*L + c) indices.
// Also zeroes the 16-byte accumulator block (stream order guarantees this
// completes before row_kernel starts).
// ---------------------------------------------------------------------------
__global__ __launch_bounds__(256) void scan_masks(const int* __restrict__ masked,
                                                  int* __restrict__ rowcol,
                                                  float* __restrict__ accum) {
  __shared__ int cnt[256];
  const int tid = threadIdx.x;
  if (tid < 4) accum[tid] = 0.0f;    // {swl, sw, sul, ticket(int 0)}
  const int per = BL / 256;          // 32 positions per thread, contiguous
  const int base = tid * per;
  int c = 0;
  for (int k = 0; k < per; ++k) c += (masked[base + k] == MASK_ID) ? 1 : 0;
  cnt[tid] = c;
  __syncthreads();
  // Hillis-Steele inclusive scan over 256 counts
  for (int off = 1; off < 256; off <<= 1) {
    int t = (tid >= off) ? cnt[tid - off] : 0;
    __syncthreads();
    cnt[tid] += t;
    __syncthreads();
  }
  int w = cnt[tid] - c;              // exclusive prefix
  for (int k = 0; k < per; ++k) {
    int p = base + k;
    if (masked[p] == MASK_ID) {
      if (w < NROWS) rowcol[w] = p;  // p == b*SEQ_L + col (row-major order)
      ++w;
    }
  }
}

// ---------------------------------------------------------------------------
// Kernel 2: per-row softmax stats + MLE term + unlikelihood term, fused with
// the final reduction (atomicAdd partials; last block via ticket computes out).
// No running-max: logits are O(10), exp cannot overflow fp32.
// ---------------------------------------------------------------------------
__global__ __launch_bounds__(256) void row_kernel(
    const float* __restrict__ pred, const int* __restrict__ target,
    const int* __restrict__ tok, const float* __restrict__ amask,
    const float* __restrict__ weight, const int* __restrict__ rowcol,
    float* __restrict__ accum, float* __restrict__ out) {
  const int i = blockIdx.x;
  const int tid = threadIdx.x;
  const float* __restrict__ row = pred + (size_t)i * CLS;

  // ---- alignment peel: row base is 8B-aligned; mod-16 is 0 or 8 ----
  const int head = ((uintptr_t)row & 15) ? 2 : 0;  // 0 or 2 floats
  const float4* __restrict__ row4 = (const float4*)(row + head);
  const int n4 = (CLS - head) >> 2;                // 7630 either way
  const int tail = CLS - head - (n4 << 2);         // 2 or 0

  float s = 0.f, xs = 0.f;
  for (int j = tid; j < n4; j += 256) {
    float4 v = row4[j];
    xs += (v.x + v.y) + (v.z + v.w);
    s += (__expf(v.x) + __expf(v.y)) + (__expf(v.z) + __expf(v.w));
  }
  if (tid == 0) {
    for (int k = 0; k < head; ++k) { float x = row[k]; xs += x; s += __expf(x); }
  }
  if (tid == 1) {
    for (int k = CLS - tail; k < CLS; ++k) { float x = row[k]; xs += x; s += __expf(x); }
  }
  // wave (64-lane) reduction of s and xs
#pragma unroll
  for (int off = 32; off > 0; off >>= 1) {
    s += __shfl_xor(s, off);
    xs += __shfl_xor(xs, off);
  }
  __shared__ float ss[4], sx[4];
  __shared__ float s_logZ, s_xsum;
  const int wid = tid >> 6, lane = tid & 63;
  if (lane == 0) { ss[wid] = s; sx[wid] = xs; }
  __syncthreads();
  if (tid == 0) {
    float S = ss[0] + ss[1] + ss[2] + ss[3];
    s_logZ = logf(S);
    s_xsum = sx[0] + sx[1] + sx[2] + sx[3];
  }
  __syncthreads();
  const float logZ = s_logZ;

  // ---- unlikelihood negative-target construction (exact reference replica) ----
  const int rc = rowcol[i];
  const int b = rc >> 7;             // / SEQ_L
  const int c = rc & (SEQ_L - 1);    // % SEQ_L
  __shared__ float s_ai[SEQ_L], s_nc[SEQ_L], s_pm[SEQ_L];
  float a = 0.f, ai = 0.f, nw = 0.f, nc_ = 0.f;
  if (tid < SEQ_L) {
    a = amask[b * SEQ_L + tid];
    ai = a * (float)tok[b * SEQ_L + tid];
    s_ai[tid] = ai;
  }
  __syncthreads();
  const float center = s_ai[c];
  if (tid < SEQ_L) {
    nw = a - ((ai == center) ? 1.f : 0.f);
    nc_ = ai * nw;                    // stage-1 neg_cand
    s_nc[tid] = nc_;
  }
  __syncthreads();
  const float prevv = s_nc[(c + SEQ_L - 1) & (SEQ_L - 1)];  // neg_cand[c-1] (wraps like jnp)
  if (tid < SEQ_L) s_pm[tid] = (nc_ == prevv) ? 1.f : 0.f;  // prev_mask (on stage-1 nc)
  __syncthreads();
  float ul = 0.f;
  if (tid < SEQ_L) {
    float nwf, ncf;
    if (c > 0) {                      // use_ngram
      float nm = s_pm[(tid + SEQ_L - 1) & (SEQ_L - 1)];     // roll(prev_mask, 1)
      float nw2 = nw + nm * nw;
      nwf = nw2;
      ncf = ai * ((nw2 != 0.f) ? 1.f : 0.f);
    } else {
      nwf = nw;
      ncf = nc_;
    }
    if (nwf != 0.f) {
      int k = (int)ncf;               // exact integer-valued float
      float p = __expf(row[k] - logZ);
      float omp = fmaxf(1.f - p, 1e-5f);
      ul = -logf(omp) * nwf;
    }
  }
#pragma unroll
  for (int off = 32; off > 0; off >>= 1) ul += __shfl_xor(ul, off);
  __shared__ float su[4];
  if (lane == 0) su[wid] = ul;
  __syncthreads();
  if (tid == 0) {
    float U = su[0] + su[1] + su[2] + su[3];
    int t = target[i];
    float lp_t = row[t] - logZ;
    float sum_logp = s_xsum - (float)CLS * logZ;
    float wv = weight[t];
    const float conf = 0.8f;                       // 1 - SMOOTHING
    const float smooth_per = 0.2f / (float)(CLS - 1);
    float wl = -(smooth_per * (sum_logp - lp_t) + conf * lp_t) * wv;

    // fused final reduction: device-scope atomics + last-block ticket
    atomicAdd(&accum[0], wl);
    atomicAdd(&accum[1], wv);
    atomicAdd(&accum[2], U);
    __threadfence();
    int old = atomicAdd((int*)&accum[3], 1);
    if (old == NROWS - 1) {
      __threadfence();
      float SWL = atomicAdd(&accum[0], 0.0f);  // coherent read of final value
      float SW  = atomicAdd(&accum[1], 0.0f);
      float SUL = atomicAdd(&accum[2], 0.0f);
      float mle = SWL / SW;
      float u = SUL / (float)NROWS;
      out[0] = mle + 1.0f * u;   // RANK_ALPHA = 1.0
      out[1] = mle;
      out[2] = u;
    }
  }
}

extern "C" void kernel_launch(void* const* d_in, const int* in_sizes, int n_in,
                              void* d_out, int out_size, void* d_ws, size_t ws_size,
                              hipStream_t stream) {
  const float* pred   = (const float*)d_in[0];
  const int*   target = (const int*)d_in[1];
  const int*   tok    = (const int*)d_in[2];
  const float* amask  = (const float*)d_in[3];
  const int*   masked = (const int*)d_in[4];
  const float* weight = (const float*)d_in[5];
  float* out = (float*)d_out;

  int*   rowcol = (int*)d_ws;
  float* accum  = (float*)((char*)d_ws + (size_t)NROWS * 4);  // {swl, sw, sul, ticket}

  scan_masks<<<1, 256, 0, stream>>>(masked, rowcol, accum);
  row_kernel<<<NROWS, 256, 0, stream>>>(pred, target, tok, amask, weight, rowcol,
                                        accum, out);
}

// Round 4
// 359.315 us; speedup vs baseline: 1.2586x; 1.2586x over previous
//
#include <hip/hip_runtime.h>
#include <stdint.h>

#define MASK_ID 103
#define CLS 30522
#define SEQ_L 128
#define NROWS 2048
#define BL 8192   // B*L

// ---------------------------------------------------------------------------
// Kernel 1: row-major nonzero(masked == MASK_ID) -> packed (b*L + c) indices
// ---------------------------------------------------------------------------
__global__ __launch_bounds__(256) void scan_masks(const int* __restrict__ masked,
                                                  int* __restrict__ rowcol) {
  __shared__ int cnt[256];
  const int tid = threadIdx.x;
  const int per = BL / 256;          // 32 positions per thread, contiguous
  const int base = tid * per;
  int c = 0;
  for (int k = 0; k < per; ++k) c += (masked[base + k] == MASK_ID) ? 1 : 0;
  cnt[tid] = c;
  __syncthreads();
  for (int off = 1; off < 256; off <<= 1) {
    int t = (tid >= off) ? cnt[tid - off] : 0;
    __syncthreads();
    cnt[tid] += t;
    __syncthreads();
  }
  int w = cnt[tid] - c;              // exclusive prefix
  for (int k = 0; k < per; ++k) {
    int p = base + k;
    if (masked[p] == MASK_ID) {
      if (w < NROWS) rowcol[w] = p;  // p == b*SEQ_L + col (row-major order)
      ++w;
    }
  }
}

// ---------------------------------------------------------------------------
// Kernel 2: per-row softmax stats + MLE term + unlikelihood term.
// Main loop batches 8 independent float4 loads into registers before any
// consumption: 8 KB in flight per wave (vs 1 KB with the naive loop the
// compiler emitted at VGPR_Count=12), so the stream runs at memory rate
// instead of one-load-latency per iteration.
// ---------------------------------------------------------------------------
__global__ __launch_bounds__(256) void row_kernel(
    const float* __restrict__ pred, const int* __restrict__ target,
    const int* __restrict__ tok, const float* __restrict__ amask,
    const float* __restrict__ weight, const int* __restrict__ rowcol,
    float* __restrict__ o_wl, float* __restrict__ o_w, float* __restrict__ o_ul) {
  const int i = blockIdx.x;
  const int tid = threadIdx.x;
  const float* __restrict__ row = pred + (size_t)i * CLS;

  // alignment peel: row base is 8B-aligned; mod-16 is 0 or 8
  const int head = ((uintptr_t)row & 15) ? 2 : 0;  // 0 or 2 floats
  const float4* __restrict__ row4 = (const float4*)(row + head);
  const int n4 = (CLS - head) >> 2;                // 7630 either way
  const int tail = CLS - head - (n4 << 2);         // 2 or 0

  float sAcc[4] = {0.f, 0.f, 0.f, 0.f};
  float xAcc[4] = {0.f, 0.f, 0.f, 0.f};
  int j = tid;
  // 8 loads in flight per iteration
  for (; j + 7 * 256 < n4; j += 8 * 256) {
    float4 v[8];
#pragma unroll
    for (int u = 0; u < 8; ++u) v[u] = row4[j + u * 256];
#pragma unroll
    for (int u = 0; u < 8; ++u) {
      xAcc[u & 3] += (v[u].x + v[u].y) + (v[u].z + v[u].w);
      sAcc[u & 3] += (__expf(v[u].x) + __expf(v[u].y)) +
                     (__expf(v[u].z) + __expf(v[u].w));
    }
  }
  for (; j < n4; j += 256) {
    float4 v = row4[j];
    xAcc[0] += (v.x + v.y) + (v.z + v.w);
    sAcc[0] += (__expf(v.x) + __expf(v.y)) + (__expf(v.z) + __expf(v.w));
  }
  float s = (sAcc[0] + sAcc[1]) + (sAcc[2] + sAcc[3]);
  float xs = (xAcc[0] + xAcc[1]) + (xAcc[2] + xAcc[3]);
  if (tid == 0) {
    for (int k = 0; k < head; ++k) { float x = row[k]; xs += x; s += __expf(x); }
  }
  if (tid == 1) {
    for (int k = CLS - tail; k < CLS; ++k) { float x = row[k]; xs += x; s += __expf(x); }
  }
  // wave (64-lane) reduction
#pragma unroll
  for (int off = 32; off > 0; off >>= 1) {
    s += __shfl_xor(s, off);
    xs += __shfl_xor(xs, off);
  }
  __shared__ float ss[4], sx[4];
  __shared__ float s_logZ, s_xsum;
  const int wid = tid >> 6, lane = tid & 63;
  if (lane == 0) { ss[wid] = s; sx[wid] = xs; }
  __syncthreads();
  if (tid == 0) {
    float S = ss[0] + ss[1] + ss[2] + ss[3];
    s_logZ = logf(S);
    s_xsum = sx[0] + sx[1] + sx[2] + sx[3];
  }
  __syncthreads();
  const float logZ = s_logZ;

  // ---- unlikelihood negative-target construction (exact reference replica) ----
  const int rc = rowcol[i];
  const int b = rc >> 7;             // / SEQ_L
  const int c = rc & (SEQ_L - 1);    // % SEQ_L
  __shared__ float s_ai[SEQ_L], s_nc[SEQ_L], s_pm[SEQ_L];
  float a = 0.f, ai = 0.f, nw = 0.f, nc_ = 0.f;
  if (tid < SEQ_L) {
    a = amask[b * SEQ_L + tid];
    ai = a * (float)tok[b * SEQ_L + tid];
    s_ai[tid] = ai;
  }
  __syncthreads();
  const float center = s_ai[c];
  if (tid < SEQ_L) {
    nw = a - ((ai == center) ? 1.f : 0.f);
    nc_ = ai * nw;                    // stage-1 neg_cand
    s_nc[tid] = nc_;
  }
  __syncthreads();
  const float prevv = s_nc[(c + SEQ_L - 1) & (SEQ_L - 1)];  // neg_cand[c-1] (wraps like jnp)
  if (tid < SEQ_L) s_pm[tid] = (nc_ == prevv) ? 1.f : 0.f;  // prev_mask (on stage-1 nc)
  __syncthreads();
  float ul = 0.f;
  if (tid < SEQ_L) {
    float nwf, ncf;
    if (c > 0) {                      // use_ngram
      float nm = s_pm[(tid + SEQ_L - 1) & (SEQ_L - 1)];     // roll(prev_mask, 1)
      float nw2 = nw + nm * nw;
      nwf = nw2;
      ncf = ai * ((nw2 != 0.f) ? 1.f : 0.f);
    } else {
      nwf = nw;
      ncf = nc_;
    }
    if (nwf != 0.f) {
      int k = (int)ncf;               // exact integer-valued float
      float p = __expf(row[k] - logZ);
      float omp = fmaxf(1.f - p, 1e-5f);
      ul = -logf(omp) * nwf;
    }
  }
#pragma unroll
  for (int off = 32; off > 0; off >>= 1) ul += __shfl_xor(ul, off);
  __shared__ float su[4];
  if (lane == 0) su[wid] = ul;
  __syncthreads();
  if (tid == 0) {
    float U = su[0] + su[1] + su[2] + su[3];
    int t = target[i];
    float lp_t = row[t] - logZ;
    float sum_logp = s_xsum - (float)CLS * logZ;
    float wv = weight[t];
    const float conf = 0.8f;                       // 1 - SMOOTHING
    const float smooth_per = 0.2f / (float)(CLS - 1);
    float wl = -(smooth_per * (sum_logp - lp_t) + conf * lp_t) * wv;
    o_wl[i] = wl;
    o_w[i] = wv;
    o_ul[i] = U;
  }
}

// ---------------------------------------------------------------------------
// Kernel 3: final reduction over 2048 rows -> (loss, mle, ul)
// (separate kernel: fusing via same-line device atomics cost ~90us in R3)
// ---------------------------------------------------------------------------
__global__ __launch_bounds__(256) void finalize_kernel(
    const float* __restrict__ wl, const float* __restrict__ wv,
    const float* __restrict__ ul, float* __restrict__ out) {
  const int tid = threadIdx.x;
  float swl = 0.f, sw = 0.f, sul = 0.f;
  for (int j = tid; j < NROWS; j += 256) {
    swl += wl[j];
    sw += wv[j];
    sul += ul[j];
  }
#pragma unroll
  for (int off = 32; off > 0; off >>= 1) {
    swl += __shfl_xor(swl, off);
    sw += __shfl_xor(sw, off);
    sul += __shfl_xor(sul, off);
  }
  __shared__ float a0[4], a1[4], a2[4];
  const int wid = tid >> 6, lane = tid & 63;
  if (lane == 0) { a0[wid] = swl; a1[wid] = sw; a2[wid] = sul; }
  __syncthreads();
  if (tid == 0) {
    float SWL = a0[0] + a0[1] + a0[2] + a0[3];
    float SW  = a1[0] + a1[1] + a1[2] + a1[3];
    float SUL = a2[0] + a2[1] + a2[2] + a2[3];
    float mle = SWL / SW;
    float u = SUL / (float)NROWS;
    out[0] = mle + 1.0f * u;   // RANK_ALPHA = 1.0
    out[1] = mle;
    out[2] = u;
  }
}

extern "C" void kernel_launch(void* const* d_in, const int* in_sizes, int n_in,
                              void* d_out, int out_size, void* d_ws, size_t ws_size,
                              hipStream_t stream) {
  const float* pred   = (const float*)d_in[0];
  const int*   target = (const int*)d_in[1];
  const int*   tok    = (const int*)d_in[2];
  const float* amask  = (const float*)d_in[3];
  const int*   masked = (const int*)d_in[4];
  const float* weight = (const float*)d_in[5];
  float* out = (float*)d_out;

  int*   rowcol = (int*)d_ws;
  float* wl = (float*)((char*)d_ws + (size_t)NROWS * 4);
  float* wv = (float*)((char*)d_ws + (size_t)NROWS * 8);
  float* ul = (float*)((char*)d_ws + (size_t)NROWS * 12);

  scan_masks<<<1, 256, 0, stream>>>(masked, rowcol);
  row_kernel<<<NROWS, 256, 0, stream>>>(pred, target, tok, amask, weight, rowcol,
                                        wl, wv, ul);
  finalize_kernel<<<1, 256, 0, stream>>>(wl, wv, ul, out);
}